// Round 1
// baseline (389139.819 us; speedup 1.0000x reference)
//
#include <hip/hip_runtime.h>
#include <cstdio>
#include <cstdint>
#include <cstddef>

// FPLSTM: T=8192 steps, IN=2048, M=2048.
//  Kernel 1: init  (zero h, flags)
//  Kernel 2: gemm  xg[t,n] = inputs[t,:]·Wx[n,:] + bx[n], stored bf16 (fp32 math)
//  Kernel 3: persistent cooperative recurrence, 256 blocks (1/CU) x 512 thr,
//            all recurrent weights in VGPRs (fp32), flag-based grid barriers.

#define T_STEPS 8192
#define MEM     2048
#define NG5     10240   // 5*MEM
#define NBLK    256
#define NTHR    512

static constexpr size_t XG_BYTES = (size_t)T_STEPS * NG5 * 2;   // bf16 xg
static constexpr size_t H_OFF    = XG_BYTES;                    // 2048 f32
static constexpr size_t A_OFF    = H_OFF + 8192;                // 2048 f32
static constexpr size_t F_OFF    = A_OFF + 8192;                // 256 int
static constexpr size_t WS_NEEDED = F_OFF + 1024;

__device__ __forceinline__ float bf2f(unsigned short u) {
  return __uint_as_float(((unsigned int)u) << 16);
}
__device__ __forceinline__ unsigned short f2bf(float f) {
  unsigned int u = __float_as_uint(f);
  u += 0x7FFFu + ((u >> 16) & 1u);   // RNE; inputs finite
  return (unsigned short)(u >> 16);
}
__device__ __forceinline__ float sigmoidf_(float x) {
  return 1.0f / (1.0f + __expf(-x));
}
__device__ __forceinline__ float tanhf_(float x) {
  x = fminf(fmaxf(x, -15.0f), 15.0f);   // clamp: avoids inf/inf, tanh(15)=1-1e-13
  float e = __expf(2.0f * x);
  return (e - 1.0f) / (e + 1.0f);
}

// ---------------------------------------------------------------- init
__global__ void fplstm_init(float* hbuf, int* flags) {
  const int tid = threadIdx.x;
  for (int i = tid; i < MEM; i += 256) hbuf[i] = 0.0f;
  flags[tid] = 0;
}

// ---------------------------------------------------------------- GEMM
// C(8192x10240) = A(8192x2048) @ W(10240x2048)^T + bx ; write bf16.
// 128x128 tile, 256 threads, 8x8 microtile, BK=16. fp32 VALU (no fp32 MFMA).
__global__ __launch_bounds__(256, 2) void fplstm_gemm(
    const float* __restrict__ A, const float* __restrict__ W,
    const float* __restrict__ bx, unsigned short* __restrict__ xg)
{
  __shared__ float As[16][132];   // [k][m], pad -> 2-way max on writes (free)
  __shared__ float Bs[16][144];   // [k][n_mapped], n + 4*(n>>5) swizzle
  const int tid = threadIdx.x;
  const int bn = blockIdx.x;      // 80 N-tiles
  const int bm = blockIdx.y;      // 64 M-tiles
  const int tx = tid & 15, ty = tid >> 4;
  const int lrow = tid >> 1;            // 0..127
  const int kh   = (tid & 1) * 8;       // 0 or 8
  const float* Ap = A + (size_t)(bm * 128 + lrow) * 2048 + kh;
  const float* Wp = W + (size_t)(bn * 128 + lrow) * 2048 + kh;
  const int bmap = lrow + 4 * (lrow >> 5);      // Bs store column
  const int bb   = 8 * tx + 4 * (tx >> 2);      // Bs read column

  float acc[8][8];
#pragma unroll
  for (int i = 0; i < 8; ++i)
#pragma unroll
    for (int j = 0; j < 8; ++j) acc[i][j] = 0.0f;

  for (int k0 = 0; k0 < 2048; k0 += 16) {
    float4 a0 = *(const float4*)(Ap + k0);
    float4 a1 = *(const float4*)(Ap + k0 + 4);
    float4 b0 = *(const float4*)(Wp + k0);
    float4 b1 = *(const float4*)(Wp + k0 + 4);
    __syncthreads();   // prev-iter readers done
    As[kh+0][lrow] = a0.x; As[kh+1][lrow] = a0.y; As[kh+2][lrow] = a0.z; As[kh+3][lrow] = a0.w;
    As[kh+4][lrow] = a1.x; As[kh+5][lrow] = a1.y; As[kh+6][lrow] = a1.z; As[kh+7][lrow] = a1.w;
    Bs[kh+0][bmap] = b0.x; Bs[kh+1][bmap] = b0.y; Bs[kh+2][bmap] = b0.z; Bs[kh+3][bmap] = b0.w;
    Bs[kh+4][bmap] = b1.x; Bs[kh+5][bmap] = b1.y; Bs[kh+6][bmap] = b1.z; Bs[kh+7][bmap] = b1.w;
    __syncthreads();
#pragma unroll
    for (int k = 0; k < 16; ++k) {
      float4 x0 = *(const float4*)(&As[k][8 * ty]);
      float4 x1 = *(const float4*)(&As[k][8 * ty + 4]);
      float4 y0 = *(const float4*)(&Bs[k][bb]);
      float4 y1 = *(const float4*)(&Bs[k][bb + 4]);
      float xa[8] = {x0.x, x0.y, x0.z, x0.w, x1.x, x1.y, x1.z, x1.w};
      float yb[8] = {y0.x, y0.y, y0.z, y0.w, y1.x, y1.y, y1.z, y1.w};
#pragma unroll
      for (int i = 0; i < 8; ++i)
#pragma unroll
        for (int j = 0; j < 8; ++j)
          acc[i][j] = fmaf(xa[i], yb[j], acc[i][j]);
    }
  }

  float bxa[8];
  {
    float4 q0 = *(const float4*)(bx + bn * 128 + 8 * tx);
    float4 q1 = *(const float4*)(bx + bn * 128 + 8 * tx + 4);
    bxa[0]=q0.x; bxa[1]=q0.y; bxa[2]=q0.z; bxa[3]=q0.w;
    bxa[4]=q1.x; bxa[5]=q1.y; bxa[6]=q1.z; bxa[7]=q1.w;
  }
#pragma unroll
  for (int i = 0; i < 8; ++i) {
    const size_t row = (size_t)(bm * 128 + 8 * ty + i);
    unsigned short t8[8];
#pragma unroll
    for (int j = 0; j < 8; ++j) t8[j] = f2bf(acc[i][j] + bxa[j]);
    unsigned short* p = xg + row * NG5 + bn * 128 + 8 * tx;
    *(ushort4*)(p)     = make_ushort4(t8[0], t8[1], t8[2], t8[3]);
    *(ushort4*)(p + 4) = make_ushort4(t8[4], t8[5], t8[6], t8[7]);
  }
}

// ---------------------------------------------------------------- recurrence
// Block b owns elements [8b,8b+8). Wave w: gate rg=w&3, column-half hf=w>>2.
// Lane columns: {1024*hf + 256*k + 4*lane + m : k<4, m<4} -> coalesced float4
// loads of h/a are exactly the lane's weight columns (no LDS for operands).
__global__ __launch_bounds__(NTHR, 2) void fplstm_recur(
    const unsigned short* __restrict__ xg,
    float* hbuf, float* abuf, int* flags,
    const float* __restrict__ Wh, const float* __restrict__ bh,
    const float* __restrict__ Wm, const float* __restrict__ bm,
    float* __restrict__ out)
{
  const int tid  = threadIdx.x;
  const int b    = blockIdx.x;
  const int w    = tid >> 6;
  const int lane = tid & 63;
  const int rg   = w & 3;
  const int hf   = w >> 2;
  const int colbase = 1024 * hf + 4 * lane;

  // ---- one-time: weights -> VGPRs (coalesced 16B/lane loads) ----
  float whr[8][16];   // 8 rows (gate rg, elems 0..7) x 16 cols
#pragma unroll
  for (int r = 0; r < 8; ++r) {
    const float* wp = Wh + (size_t)(rg * MEM + 8 * b + r) * MEM + colbase;
#pragma unroll
    for (int k = 0; k < 4; ++k) {
      float4 v = *(const float4*)(wp + 256 * k);
      whr[r][4*k+0] = v.x; whr[r][4*k+1] = v.y; whr[r][4*k+2] = v.z; whr[r][4*k+3] = v.w;
    }
  }
  float wmr[2][16];   // rows {2*rg, 2*rg+1} of block's Wm slice
#pragma unroll
  for (int r = 0; r < 2; ++r) {
    const float* wp = Wm + (size_t)(8 * b + 2 * rg + r) * MEM + colbase;
#pragma unroll
    for (int k = 0; k < 4; ++k) {
      float4 v = *(const float4*)(wp + 256 * k);
      wmr[r][4*k+0] = v.x; wmr[r][4*k+1] = v.y; wmr[r][4*k+2] = v.z; wmr[r][4*k+3] = v.w;
    }
  }

  float bhv0 = 0, bhv1 = 0, bhv2 = 0, bhv3 = 0, bmv = 0;
  if (tid < 8) {
    bhv0 = bh[0 * MEM + 8 * b + tid];
    bhv1 = bh[1 * MEM + 8 * b + tid];
    bhv2 = bh[2 * MEM + 8 * b + tid];
    bhv3 = bh[3 * MEM + 8 * b + tid];
    bmv  = bm[8 * b + tid];
  }

  __shared__ float redL[8][8];
  __shared__ float ghL[32];
  __shared__ float redM[8][2];

  float c_e = 0.0f, h_last = 0.0f;

  for (int t = 0; t < T_STEPS; ++t) {
    // prefetch xg row t (immutable; issue before poll so latency hides)
    float xv0 = 0, xv1 = 0, xv2 = 0, xv3 = 0, xv4 = 0;
    if (tid < 8) {
      const unsigned short* xp = xg + (size_t)t * NG5 + 8 * b + tid;
      xv0 = bf2f(xp[0]);
      xv1 = bf2f(xp[1 * MEM]);
      xv2 = bf2f(xp[2 * MEM]);
      xv3 = bf2f(xp[3 * MEM]);
      xv4 = bf2f(xp[4 * MEM]);
    }

    // ---- barrier: h_{t-1} fully published (phase value 2t) ----
    if (tid < NBLK) {
      while (__hip_atomic_load(&flags[tid], __ATOMIC_RELAXED,
                               __HIP_MEMORY_SCOPE_AGENT) < 2 * t) {}
    }
    __syncthreads();
    __builtin_amdgcn_fence(__ATOMIC_ACQUIRE, "agent");  // inv L1/L2 -> plain loads coherent

    // ---- phase A: gh = Wh@h (my gate rg, my half) ----
    float hreg[16];
    {
      const float4* hp = (const float4*)(hbuf + colbase);
#pragma unroll
      for (int k = 0; k < 4; ++k) {
        float4 v = hp[64 * k];
        hreg[4*k+0] = v.x; hreg[4*k+1] = v.y; hreg[4*k+2] = v.z; hreg[4*k+3] = v.w;
      }
    }
    float acc[8];
#pragma unroll
    for (int r = 0; r < 8; ++r) {
      float s = 0.0f;
#pragma unroll
      for (int j = 0; j < 16; ++j) s = fmaf(whr[r][j], hreg[j], s);
      acc[r] = s;
    }
    // reduce-scatter butterfly (10 shuffles for 8 partial rows)
    float v4[4];
    {
      const int b0 = lane & 1;
#pragma unroll
      for (int i = 0; i < 4; ++i) {
        float sent = b0 ? acc[i] : acc[4 + i];
        float got  = __shfl_xor(sent, 1, 64);
        v4[i] = (b0 ? acc[4 + i] : acc[i]) + got;
      }
    }
    float v2[2];
    {
      const int b1 = (lane >> 1) & 1;
#pragma unroll
      for (int i = 0; i < 2; ++i) {
        float sent = b1 ? v4[i] : v4[2 + i];
        float got  = __shfl_xor(sent, 2, 64);
        v2[i] = (b1 ? v4[2 + i] : v4[i]) + got;
      }
    }
    float v1;
    {
      const int b2 = (lane >> 2) & 1;
      float sent = b2 ? v2[0] : v2[1];
      float got  = __shfl_xor(sent, 4, 64);
      v1 = (b2 ? v2[1] : v2[0]) + got;
    }
    v1 += __shfl_xor(v1, 8, 64);
    v1 += __shfl_xor(v1, 16, 64);
    v1 += __shfl_xor(v1, 32, 64);
    if (lane < 8) {
      const int r = 4 * (lane & 1) + 2 * ((lane >> 1) & 1) + ((lane >> 2) & 1);
      redL[w][r] = v1;
    }
    __syncthreads();
    if (tid < 32)  // gate q=tid>>3, elem e=tid&7 ; combine two column halves
      ghL[tid] = redL[tid >> 3][tid & 7] + redL[(tid >> 3) + 4][tid & 7];
    // (tid<32 and tid<8 are wave 0: lgkmcnt ordering handled by compiler)
    float g_i = 0, g_o = 0, g_fc = 0;
    if (tid < 8) {
      float gi = sigmoidf_(xv0 + ghL[tid]      + bhv0);
      float go = sigmoidf_(xv1 + ghL[8 + tid]  + bhv1);
      float gz = sigmoidf_(xv2 + ghL[16 + tid] + bhv2);
      float gf = sigmoidf_(xv3 + ghL[24 + tid] + bhv3);
      float a_e = gz * tanhf_(c_e);
      g_i = gi; g_o = go; g_fc = gf * c_e;
      __hip_atomic_store(&abuf[8 * b + tid], a_e, __ATOMIC_RELAXED,
                         __HIP_MEMORY_SCOPE_AGENT);
    }
    __syncthreads();   // drains all threads' vmcnt before flag
    if (tid == 0)
      __hip_atomic_store(&flags[b], 2 * t + 1, __ATOMIC_RELEASE,
                         __HIP_MEMORY_SCOPE_AGENT);

    // ---- barrier: a_t published ----
    if (tid < NBLK) {
      while (__hip_atomic_load(&flags[tid], __ATOMIC_RELAXED,
                               __HIP_MEMORY_SCOPE_AGENT) < 2 * t + 1) {}
    }
    __syncthreads();
    __builtin_amdgcn_fence(__ATOMIC_ACQUIRE, "agent");

    // ---- phase B: mg = Wm@a (my 2 rows, my half) ----
    float areg[16];
    {
      const float4* ap = (const float4*)(abuf + colbase);
#pragma unroll
      for (int k = 0; k < 4; ++k) {
        float4 v = ap[64 * k];
        areg[4*k+0] = v.x; areg[4*k+1] = v.y; areg[4*k+2] = v.z; areg[4*k+3] = v.w;
      }
    }
    float am0 = 0.0f, am1 = 0.0f;
#pragma unroll
    for (int j = 0; j < 16; ++j) am0 = fmaf(wmr[0][j], areg[j], am0);
#pragma unroll
    for (int j = 0; j < 16; ++j) am1 = fmaf(wmr[1][j], areg[j], am1);
    {
      float sent = (lane & 1) ? am0 : am1;
      float got  = __shfl_xor(sent, 1, 64);
      float vv = ((lane & 1) ? am1 : am0) + got;
      vv += __shfl_xor(vv, 2, 64);
      vv += __shfl_xor(vv, 4, 64);
      vv += __shfl_xor(vv, 8, 64);
      vv += __shfl_xor(vv, 16, 64);
      vv += __shfl_xor(vv, 32, 64);
      if (lane < 2) redM[w][lane] = vv;
    }
    __syncthreads();
    if (tid < 8) {
      float mg = redM[tid >> 1][tid & 1] + redM[(tid >> 1) + 4][tid & 1];
      float u  = tanhf_(xv4 + mg + bmv);
      c_e    = fmaf(g_i, u, g_fc);
      h_last = g_o * tanhf_(c_e);
      __hip_atomic_store(&hbuf[8 * b + tid], h_last, __ATOMIC_RELAXED,
                         __HIP_MEMORY_SCOPE_AGENT);
    }
    __syncthreads();
    if (tid == 0)
      __hip_atomic_store(&flags[b], 2 * t + 2, __ATOMIC_RELEASE,
                         __HIP_MEMORY_SCOPE_AGENT);
  }

  if (tid < 8) out[8 * b + tid] = h_last;
}

// ---------------------------------------------------------------- launch
extern "C" void kernel_launch(void* const* d_in, const int* in_sizes, int n_in,
                              void* d_out, int out_size, void* d_ws, size_t ws_size,
                              hipStream_t stream) {
  const float* inputs = (const float*)d_in[0];
  const float* Wx     = (const float*)d_in[1];
  const float* bx     = (const float*)d_in[2];
  const float* Wh     = (const float*)d_in[3];
  const float* bh     = (const float*)d_in[4];
  const float* Wm     = (const float*)d_in[5];
  const float* bm     = (const float*)d_in[6];
  float* out = (float*)d_out;
  char* ws = (char*)d_ws;

  if (ws_size < WS_NEEDED) {
    fprintf(stderr, "FPLSTM: ws_size %zu < needed %zu -- cannot run\n",
            ws_size, (size_t)WS_NEEDED);
    return;
  }

  unsigned short* xg = (unsigned short*)ws;
  float* hbuf = (float*)(ws + H_OFF);
  float* abuf = (float*)(ws + A_OFF);
  int*   flags = (int*)(ws + F_OFF);

  fplstm_init<<<1, 256, 0, stream>>>(hbuf, flags);
  fplstm_gemm<<<dim3(80, 64), 256, 0, stream>>>(inputs, Wx, bx, xg);

  void* args[] = {(void*)&xg, (void*)&hbuf, (void*)&abuf, (void*)&flags,
                  (void*)&Wh, (void*)&bh, (void*)&Wm, (void*)&bm, (void*)&out};
  hipError_t e = hipLaunchCooperativeKernel((void*)fplstm_recur, dim3(NBLK),
                                            dim3(NTHR), args, 0, stream);
  if (e != hipSuccess) {
    // Fallback: 256 blocks x 512 thr (<=2 waves/SIMD) on 256 CUs is
    // co-resident in practice; spin-barrier remains sound.
    fprintf(stderr, "FPLSTM: coop launch failed (%d), plain launch\n", (int)e);
    fplstm_recur<<<dim3(NBLK), dim3(NTHR), 0, stream>>>(
        xg, hbuf, abuf, flags, Wh, bh, Wm, bm, out);
  }
}

// Round 2
// 69005.676 us; speedup vs baseline: 5.6392x; 5.6392x over previous
//
#include <hip/hip_runtime.h>
#include <cstdio>
#include <cstdint>
#include <cstddef>

// FPLSTM: T=8192 steps, IN=2048, M=2048.
//  Kernel 1: init  (zero h, flags)
//  Kernel 2: gemm  xg[t,n] = inputs[t,:]·Wx[n,:] + bx[n], stored bf16 (fp32 math)
//  Kernel 3: persistent cooperative recurrence, 256 blocks (1/CU) x 512 thr,
//            recurrent weights in VGPRs (fp32), flag-based grid barriers.
//
// R2 change: no agent fences / atomic builtins (they lower to cache-wide
// buffer_inv / L2 writeback -> 49us/step, VALUBusy 1.6% in R1). Shared words
// (h, a, flags) use per-access coherent global_load/store sc0 sc1 (L3 is the
// coherence point). Only wave 0 polls flags (dwordx4: 4 flags/lane).

#define T_STEPS 8192
#define MEM     2048
#define NG5     10240   // 5*MEM
#define NBLK    256
#define NTHR    512

static constexpr size_t XG_BYTES = (size_t)T_STEPS * NG5 * 2;   // bf16 xg
static constexpr size_t H_OFF    = XG_BYTES;                    // 2048 f32
static constexpr size_t A_OFF    = H_OFF + 8192;                // 2048 f32
static constexpr size_t F_OFF    = A_OFF + 8192;                // 256 int
static constexpr size_t WS_NEEDED = F_OFF + 1024;

__device__ __forceinline__ float bf2f(unsigned short u) {
  return __uint_as_float(((unsigned int)u) << 16);
}
__device__ __forceinline__ unsigned short f2bf(float f) {
  unsigned int u = __float_as_uint(f);
  u += 0x7FFFu + ((u >> 16) & 1u);   // RNE; inputs finite
  return (unsigned short)(u >> 16);
}
__device__ __forceinline__ float sigmoidf_(float x) {
  return 1.0f / (1.0f + __expf(-x));
}
__device__ __forceinline__ float tanhf_(float x) {
  x = fminf(fmaxf(x, -15.0f), 15.0f);
  float e = __expf(2.0f * x);
  return (e - 1.0f) / (e + 1.0f);
}

// ---- per-access coherent ops (bypass L1+L2; coherence point = L3) ----
__device__ __forceinline__ int4 load_i4_cc(const int4* p) {
  int4 r;
  asm volatile("global_load_dwordx4 %0, %1, off sc0 sc1\n\t"
               "s_waitcnt vmcnt(0)"
               : "=v"(r) : "v"(p) : "memory");
  return r;
}
__device__ __forceinline__ void load_vec16_cc(const float* p, float* o) {
  float4 a, b, c, d;
  asm volatile("global_load_dwordx4 %0, %4, off sc0 sc1\n\t"
               "global_load_dwordx4 %1, %5, off sc0 sc1\n\t"
               "global_load_dwordx4 %2, %6, off sc0 sc1\n\t"
               "global_load_dwordx4 %3, %7, off sc0 sc1\n\t"
               "s_waitcnt vmcnt(0)"
               : "=v"(a), "=v"(b), "=v"(c), "=v"(d)
               : "v"(p), "v"(p + 256), "v"(p + 512), "v"(p + 768)
               : "memory");
  o[0]=a.x; o[1]=a.y; o[2]=a.z; o[3]=a.w;
  o[4]=b.x; o[5]=b.y; o[6]=b.z; o[7]=b.w;
  o[8]=c.x; o[9]=c.y; o[10]=c.z; o[11]=c.w;
  o[12]=d.x; o[13]=d.y; o[14]=d.z; o[15]=d.w;
}
__device__ __forceinline__ void store_f_cc(float* p, float v) {
  asm volatile("global_store_dword %0, %1, off sc0 sc1"
               :: "v"(p), "v"(v) : "memory");
}
// drain data stores, then publish flag (all in wave 0 -> no barrier needed)
__device__ __forceinline__ void store_flag_cc(int* p, int v) {
  asm volatile("s_waitcnt vmcnt(0)\n\t"
               "global_store_dword %0, %1, off sc0 sc1"
               :: "v"(p), "v"(v) : "memory");
}

// ---------------------------------------------------------------- init
__global__ void fplstm_init(float* hbuf, int* flags) {
  const int tid = threadIdx.x;
  for (int i = tid; i < MEM; i += 256) hbuf[i] = 0.0f;
  flags[tid] = 0;
}

// ---------------------------------------------------------------- GEMM
// C(8192x10240) = A(8192x2048) @ W(10240x2048)^T + bx ; write bf16.
// 128x128 tile, 256 threads, 8x8 microtile, BK=16. fp32 VALU (no fp32 MFMA).
__global__ __launch_bounds__(256, 2) void fplstm_gemm(
    const float* __restrict__ A, const float* __restrict__ W,
    const float* __restrict__ bx, unsigned short* __restrict__ xg)
{
  __shared__ float As[16][132];
  __shared__ float Bs[16][144];
  const int tid = threadIdx.x;
  const int bn = blockIdx.x;      // 80 N-tiles
  const int bm = blockIdx.y;      // 64 M-tiles
  const int tx = tid & 15, ty = tid >> 4;
  const int lrow = tid >> 1;
  const int kh   = (tid & 1) * 8;
  const float* Ap = A + (size_t)(bm * 128 + lrow) * 2048 + kh;
  const float* Wp = W + (size_t)(bn * 128 + lrow) * 2048 + kh;
  const int bmap = lrow + 4 * (lrow >> 5);
  const int bb   = 8 * tx + 4 * (tx >> 2);

  float acc[8][8];
#pragma unroll
  for (int i = 0; i < 8; ++i)
#pragma unroll
    for (int j = 0; j < 8; ++j) acc[i][j] = 0.0f;

  for (int k0 = 0; k0 < 2048; k0 += 16) {
    float4 a0 = *(const float4*)(Ap + k0);
    float4 a1 = *(const float4*)(Ap + k0 + 4);
    float4 b0 = *(const float4*)(Wp + k0);
    float4 b1 = *(const float4*)(Wp + k0 + 4);
    __syncthreads();
    As[kh+0][lrow] = a0.x; As[kh+1][lrow] = a0.y; As[kh+2][lrow] = a0.z; As[kh+3][lrow] = a0.w;
    As[kh+4][lrow] = a1.x; As[kh+5][lrow] = a1.y; As[kh+6][lrow] = a1.z; As[kh+7][lrow] = a1.w;
    Bs[kh+0][bmap] = b0.x; Bs[kh+1][bmap] = b0.y; Bs[kh+2][bmap] = b0.z; Bs[kh+3][bmap] = b0.w;
    Bs[kh+4][bmap] = b1.x; Bs[kh+5][bmap] = b1.y; Bs[kh+6][bmap] = b1.z; Bs[kh+7][bmap] = b1.w;
    __syncthreads();
#pragma unroll
    for (int k = 0; k < 16; ++k) {
      float4 x0 = *(const float4*)(&As[k][8 * ty]);
      float4 x1 = *(const float4*)(&As[k][8 * ty + 4]);
      float4 y0 = *(const float4*)(&Bs[k][bb]);
      float4 y1 = *(const float4*)(&Bs[k][bb + 4]);
      float xa[8] = {x0.x, x0.y, x0.z, x0.w, x1.x, x1.y, x1.z, x1.w};
      float yb[8] = {y0.x, y0.y, y0.z, y0.w, y1.x, y1.y, y1.z, y1.w};
#pragma unroll
      for (int i = 0; i < 8; ++i)
#pragma unroll
        for (int j = 0; j < 8; ++j)
          acc[i][j] = fmaf(xa[i], yb[j], acc[i][j]);
    }
  }

  float bxa[8];
  {
    float4 q0 = *(const float4*)(bx + bn * 128 + 8 * tx);
    float4 q1 = *(const float4*)(bx + bn * 128 + 8 * tx + 4);
    bxa[0]=q0.x; bxa[1]=q0.y; bxa[2]=q0.z; bxa[3]=q0.w;
    bxa[4]=q1.x; bxa[5]=q1.y; bxa[6]=q1.z; bxa[7]=q1.w;
  }
#pragma unroll
  for (int i = 0; i < 8; ++i) {
    const size_t row = (size_t)(bm * 128 + 8 * ty + i);
    unsigned short t8[8];
#pragma unroll
    for (int j = 0; j < 8; ++j) t8[j] = f2bf(acc[i][j] + bxa[j]);
    unsigned short* p = xg + row * NG5 + bn * 128 + 8 * tx;
    *(ushort4*)(p)     = make_ushort4(t8[0], t8[1], t8[2], t8[3]);
    *(ushort4*)(p + 4) = make_ushort4(t8[4], t8[5], t8[6], t8[7]);
  }
}

// ---------------------------------------------------------------- recurrence
// Block b owns elements [8b,8b+8). Wave w: gate rg=w&3, column-half hf=w>>2.
// Lane columns: {1024*hf + 256*k + 4*lane + m : k<4, m<4} -> coalesced float4
// loads of h/a are exactly the lane's weight columns.
__global__ __launch_bounds__(NTHR, 2) void fplstm_recur(
    const unsigned short* __restrict__ xg,
    float* hbuf, float* abuf, int* flags,
    const float* __restrict__ Wh, const float* __restrict__ bh,
    const float* __restrict__ Wm, const float* __restrict__ bm,
    float* __restrict__ out)
{
  const int tid  = threadIdx.x;
  const int b    = blockIdx.x;
  const int w    = tid >> 6;
  const int lane = tid & 63;
  const int rg   = w & 3;
  const int hf   = w >> 2;
  const int colbase = 1024 * hf + 4 * lane;

  // ---- one-time: weights -> registers (coalesced 16B/lane loads) ----
  float whr[8][16];
#pragma unroll
  for (int r = 0; r < 8; ++r) {
    const float* wp = Wh + (size_t)(rg * MEM + 8 * b + r) * MEM + colbase;
#pragma unroll
    for (int k = 0; k < 4; ++k) {
      float4 v = *(const float4*)(wp + 256 * k);
      whr[r][4*k+0] = v.x; whr[r][4*k+1] = v.y; whr[r][4*k+2] = v.z; whr[r][4*k+3] = v.w;
    }
  }
  float wmr[2][16];
#pragma unroll
  for (int r = 0; r < 2; ++r) {
    const float* wp = Wm + (size_t)(8 * b + 2 * rg + r) * MEM + colbase;
#pragma unroll
    for (int k = 0; k < 4; ++k) {
      float4 v = *(const float4*)(wp + 256 * k);
      wmr[r][4*k+0] = v.x; wmr[r][4*k+1] = v.y; wmr[r][4*k+2] = v.z; wmr[r][4*k+3] = v.w;
    }
  }

  float bhv0 = 0, bhv1 = 0, bhv2 = 0, bhv3 = 0, bmv = 0;
  if (tid < 8) {
    bhv0 = bh[0 * MEM + 8 * b + tid];
    bhv1 = bh[1 * MEM + 8 * b + tid];
    bhv2 = bh[2 * MEM + 8 * b + tid];
    bhv3 = bh[3 * MEM + 8 * b + tid];
    bmv  = bm[8 * b + tid];
  }

  __shared__ float redL[8][8];
  __shared__ float ghL[32];
  __shared__ float redM[8][2];

  float c_e = 0.0f, h_last = 0.0f;
  const int4* fquad = (const int4*)flags + lane;   // wave0: 4 flags/lane

  for (int t = 0; t < T_STEPS; ++t) {
    // prefetch xg row t (immutable, plain cached loads)
    float xv0 = 0, xv1 = 0, xv2 = 0, xv3 = 0, xv4 = 0;
    if (tid < 8) {
      const unsigned short* xp = xg + (size_t)t * NG5 + 8 * b + tid;
      xv0 = bf2f(xp[0]);
      xv1 = bf2f(xp[1 * MEM]);
      xv2 = bf2f(xp[2 * MEM]);
      xv3 = bf2f(xp[3 * MEM]);
      xv4 = bf2f(xp[4 * MEM]);
    }

    // ---- barrier: h_{t-1} published (flag >= 2t); wave 0 polls ----
    if (w == 0) {
      const int tgt = 2 * t;
      for (;;) {
        int4 f = load_i4_cc(fquad);
        if (f.x >= tgt && f.y >= tgt && f.z >= tgt && f.w >= tgt) break;
      }
    }
    __syncthreads();

    // ---- phase A: gh = Wh@h (my gate rg, my half) ----
    float hreg[16];
    load_vec16_cc(hbuf + colbase, hreg);
    float acc[8];
#pragma unroll
    for (int r = 0; r < 8; ++r) {
      float s = 0.0f;
#pragma unroll
      for (int j = 0; j < 16; ++j) s = fmaf(whr[r][j], hreg[j], s);
      acc[r] = s;
    }
    // reduce-scatter butterfly
    float v4[4];
    {
      const int b0 = lane & 1;
#pragma unroll
      for (int i = 0; i < 4; ++i) {
        float sent = b0 ? acc[i] : acc[4 + i];
        float got  = __shfl_xor(sent, 1, 64);
        v4[i] = (b0 ? acc[4 + i] : acc[i]) + got;
      }
    }
    float v2[2];
    {
      const int b1 = (lane >> 1) & 1;
#pragma unroll
      for (int i = 0; i < 2; ++i) {
        float sent = b1 ? v4[i] : v4[2 + i];
        float got  = __shfl_xor(sent, 2, 64);
        v2[i] = (b1 ? v4[2 + i] : v4[i]) + got;
      }
    }
    float v1;
    {
      const int b2 = (lane >> 2) & 1;
      float sent = b2 ? v2[0] : v2[1];
      float got  = __shfl_xor(sent, 4, 64);
      v1 = (b2 ? v2[1] : v2[0]) + got;
    }
    v1 += __shfl_xor(v1, 8, 64);
    v1 += __shfl_xor(v1, 16, 64);
    v1 += __shfl_xor(v1, 32, 64);
    if (lane < 8) {
      const int r = 4 * (lane & 1) + 2 * ((lane >> 1) & 1) + ((lane >> 2) & 1);
      redL[w][r] = v1;
    }
    __syncthreads();

    // ---- wave 0: gates, publish a, flag; then poll a-barrier ----
    float g_i = 0, g_o = 0, g_fc = 0;
    if (w == 0) {
      if (tid < 32)
        ghL[tid] = redL[tid >> 3][tid & 7] + redL[(tid >> 3) + 4][tid & 7];
      if (tid < 8) {
        float gi = sigmoidf_(xv0 + ghL[tid]      + bhv0);
        float go = sigmoidf_(xv1 + ghL[8 + tid]  + bhv1);
        float gz = sigmoidf_(xv2 + ghL[16 + tid] + bhv2);
        float gf = sigmoidf_(xv3 + ghL[24 + tid] + bhv3);
        float a_e = gz * tanhf_(c_e);
        g_i = gi; g_o = go; g_fc = gf * c_e;
        store_f_cc(&abuf[8 * b + tid], a_e);
      }
      if (tid == 0) store_flag_cc(&flags[b], 2 * t + 1);
      const int tgt = 2 * t + 1;
      for (;;) {
        int4 f = load_i4_cc(fquad);
        if (f.x >= tgt && f.y >= tgt && f.z >= tgt && f.w >= tgt) break;
      }
    }
    __syncthreads();

    // ---- phase B: mg = Wm@a (my 2 rows, my half) ----
    float areg[16];
    load_vec16_cc(abuf + colbase, areg);
    float am0 = 0.0f, am1 = 0.0f;
#pragma unroll
    for (int j = 0; j < 16; ++j) am0 = fmaf(wmr[0][j], areg[j], am0);
#pragma unroll
    for (int j = 0; j < 16; ++j) am1 = fmaf(wmr[1][j], areg[j], am1);
    {
      float sent = (lane & 1) ? am0 : am1;
      float got  = __shfl_xor(sent, 1, 64);
      float vv = ((lane & 1) ? am1 : am0) + got;
      vv += __shfl_xor(vv, 2, 64);
      vv += __shfl_xor(vv, 4, 64);
      vv += __shfl_xor(vv, 8, 64);
      vv += __shfl_xor(vv, 16, 64);
      vv += __shfl_xor(vv, 32, 64);
      if (lane < 2) redM[w][lane] = vv;
    }
    __syncthreads();
    if (w == 0) {
      if (tid < 8) {
        float mg = redM[tid >> 1][tid & 1] + redM[(tid >> 1) + 4][tid & 1];
        float u  = tanhf_(xv4 + mg + bmv);
        c_e    = fmaf(g_i, u, g_fc);
        h_last = g_o * tanhf_(c_e);
        store_f_cc(&hbuf[8 * b + tid], h_last);
      }
      if (tid == 0) store_flag_cc(&flags[b], 2 * t + 2);
    }
    // no block-wide barrier needed here: next-iter __syncthreads after poll
  }

  if (tid < 8) out[8 * b + tid] = h_last;
}

// ---------------------------------------------------------------- launch
extern "C" void kernel_launch(void* const* d_in, const int* in_sizes, int n_in,
                              void* d_out, int out_size, void* d_ws, size_t ws_size,
                              hipStream_t stream) {
  const float* inputs = (const float*)d_in[0];
  const float* Wx     = (const float*)d_in[1];
  const float* bx     = (const float*)d_in[2];
  const float* Wh     = (const float*)d_in[3];
  const float* bh     = (const float*)d_in[4];
  const float* Wm     = (const float*)d_in[5];
  const float* bm     = (const float*)d_in[6];
  float* out = (float*)d_out;
  char* ws = (char*)d_ws;

  if (ws_size < WS_NEEDED) {
    fprintf(stderr, "FPLSTM: ws_size %zu < needed %zu -- cannot run\n",
            ws_size, (size_t)WS_NEEDED);
    return;
  }

  unsigned short* xg = (unsigned short*)ws;
  float* hbuf = (float*)(ws + H_OFF);
  float* abuf = (float*)(ws + A_OFF);
  int*   flags = (int*)(ws + F_OFF);

  fplstm_init<<<1, 256, 0, stream>>>(hbuf, flags);
  fplstm_gemm<<<dim3(80, 64), 256, 0, stream>>>(inputs, Wx, bx, xg);

  void* args[] = {(void*)&xg, (void*)&hbuf, (void*)&abuf, (void*)&flags,
                  (void*)&Wh, (void*)&bh, (void*)&Wm, (void*)&bm, (void*)&out};
  hipError_t e = hipLaunchCooperativeKernel((void*)fplstm_recur, dim3(NBLK),
                                            dim3(NTHR), args, 0, stream);
  if (e != hipSuccess) {
    fprintf(stderr, "FPLSTM: coop launch failed (%d), plain launch\n", (int)e);
    fplstm_recur<<<dim3(NBLK), dim3(NTHR), 0, stream>>>(
        xg, hbuf, abuf, flags, Wh, bh, Wm, bm, out);
  }
}

// Round 3
// 63087.714 us; speedup vs baseline: 6.1682x; 1.0938x over previous
//
#include <hip/hip_runtime.h>
#include <cstdio>
#include <cstdint>
#include <cstddef>

// FPLSTM: T=8192 steps, IN=2048, M=2048.
//  Kernel 1: init  (zero replicated h/a line arrays)
//  Kernel 2: gemm  xg[t,n] = inputs[t,:]·Wx[n,:] + bx[n], stored bf16
//  Kernel 3: persistent cooperative recurrence, 256 blocks x 512 thr.
//
// R3: the 8us/step was L3 fan-out congestion (each h-line requested ~1024x
// per phase; flag lines hammered). Now: (a) h/a replicated into 8 copies,
// block b reads copy b&7; (b) each wave loads a distinct slice ONCE and
// redistributes via LDS; (c) tag+data fused in one 64B line per block per
// copy {8 floats, int tag} -> poll IS the data load (one RTT). Tags are
// monotonic ints; writer can't lap a reader (reader must publish its own
// slice -- which requires consuming -- before the writer's next phase).

#define T_STEPS 8192
#define MEM     2048
#define NG5     10240   // 5*MEM
#define NBLK    256
#define NTHR    512
#define RCOPY   8

// line = 16 dwords: f[0..7] = dwords 0..7, tag = dword 8, pad 9..15
static constexpr size_t XG_BYTES  = (size_t)T_STEPS * NG5 * 2;     // bf16 xg
static constexpr size_t HREP_OFF  = XG_BYTES;                       // 8*256*64 B
static constexpr size_t REP_BYTES = (size_t)RCOPY * NBLK * 64;
static constexpr size_t AREP_OFF  = HREP_OFF + REP_BYTES;
static constexpr size_t WS_NEEDED = AREP_OFF + REP_BYTES;

__device__ __forceinline__ float bf2f(unsigned short u) {
  return __uint_as_float(((unsigned int)u) << 16);
}
__device__ __forceinline__ unsigned short f2bf(float f) {
  unsigned int u = __float_as_uint(f);
  u += 0x7FFFu + ((u >> 16) & 1u);   // RNE; inputs finite
  return (unsigned short)(u >> 16);
}
__device__ __forceinline__ float sigmoidf_(float x) {
  return 1.0f / (1.0f + __expf(-x));
}
__device__ __forceinline__ float tanhf_(float x) {
  x = fminf(fmaxf(x, -15.0f), 15.0f);
  float e = __expf(2.0f * x);
  return (e - 1.0f) / (e + 1.0f);
}

// ---- per-access coherent ops (bypass L1+L2; coherence point = L3) ----
__device__ __forceinline__ void store_f_cc(float* p, float v) {
  asm volatile("global_store_dword %0, %1, off sc0 sc1"
               :: "v"(p), "v"(v) : "memory");
}
__device__ __forceinline__ void store_i_cc(int* p, int v) {
  asm volatile("global_store_dword %0, %1, off sc0 sc1"
               :: "v"(p), "v"(v) : "memory");
}
__device__ __forceinline__ void drain_stores() {
  asm volatile("s_waitcnt vmcnt(0)" ::: "memory");
}

// ---------------------------------------------------------------- init
__global__ void fplstm_init(int* rep) {   // zero hrep+arep (2*RCOPY*NBLK*16 dwords)
  const int tid = threadIdx.x;
  const int n = 2 * RCOPY * NBLK * 16;
  for (int i = tid; i < n; i += 256) rep[i] = 0;
}

// ---------------------------------------------------------------- GEMM
// C(8192x10240) = A(8192x2048) @ W(10240x2048)^T + bx ; write bf16.
__global__ __launch_bounds__(256, 2) void fplstm_gemm(
    const float* __restrict__ A, const float* __restrict__ W,
    const float* __restrict__ bx, unsigned short* __restrict__ xg)
{
  __shared__ float As[16][132];
  __shared__ float Bs[16][144];
  const int tid = threadIdx.x;
  const int bn = blockIdx.x;      // 80 N-tiles
  const int bm = blockIdx.y;      // 64 M-tiles
  const int tx = tid & 15, ty = tid >> 4;
  const int lrow = tid >> 1;
  const int kh   = (tid & 1) * 8;
  const float* Ap = A + (size_t)(bm * 128 + lrow) * 2048 + kh;
  const float* Wp = W + (size_t)(bn * 128 + lrow) * 2048 + kh;
  const int bmap = lrow + 4 * (lrow >> 5);
  const int bb   = 8 * tx + 4 * (tx >> 2);

  float acc[8][8];
#pragma unroll
  for (int i = 0; i < 8; ++i)
#pragma unroll
    for (int j = 0; j < 8; ++j) acc[i][j] = 0.0f;

  for (int k0 = 0; k0 < 2048; k0 += 16) {
    float4 a0 = *(const float4*)(Ap + k0);
    float4 a1 = *(const float4*)(Ap + k0 + 4);
    float4 b0 = *(const float4*)(Wp + k0);
    float4 b1 = *(const float4*)(Wp + k0 + 4);
    __syncthreads();
    As[kh+0][lrow] = a0.x; As[kh+1][lrow] = a0.y; As[kh+2][lrow] = a0.z; As[kh+3][lrow] = a0.w;
    As[kh+4][lrow] = a1.x; As[kh+5][lrow] = a1.y; As[kh+6][lrow] = a1.z; As[kh+7][lrow] = a1.w;
    Bs[kh+0][bmap] = b0.x; Bs[kh+1][bmap] = b0.y; Bs[kh+2][bmap] = b0.z; Bs[kh+3][bmap] = b0.w;
    Bs[kh+4][bmap] = b1.x; Bs[kh+5][bmap] = b1.y; Bs[kh+6][bmap] = b1.z; Bs[kh+7][bmap] = b1.w;
    __syncthreads();
#pragma unroll
    for (int k = 0; k < 16; ++k) {
      float4 x0 = *(const float4*)(&As[k][8 * ty]);
      float4 x1 = *(const float4*)(&As[k][8 * ty + 4]);
      float4 y0 = *(const float4*)(&Bs[k][bb]);
      float4 y1 = *(const float4*)(&Bs[k][bb + 4]);
      float xa[8] = {x0.x, x0.y, x0.z, x0.w, x1.x, x1.y, x1.z, x1.w};
      float yb[8] = {y0.x, y0.y, y0.z, y0.w, y1.x, y1.y, y1.z, y1.w};
#pragma unroll
      for (int i = 0; i < 8; ++i)
#pragma unroll
        for (int j = 0; j < 8; ++j)
          acc[i][j] = fmaf(xa[i], yb[j], acc[i][j]);
    }
  }

  float bxa[8];
  {
    float4 q0 = *(const float4*)(bx + bn * 128 + 8 * tx);
    float4 q1 = *(const float4*)(bx + bn * 128 + 8 * tx + 4);
    bxa[0]=q0.x; bxa[1]=q0.y; bxa[2]=q0.z; bxa[3]=q0.w;
    bxa[4]=q1.x; bxa[5]=q1.y; bxa[6]=q1.z; bxa[7]=q1.w;
  }
#pragma unroll
  for (int i = 0; i < 8; ++i) {
    const size_t row = (size_t)(bm * 128 + 8 * ty + i);
    unsigned short t8[8];
#pragma unroll
    for (int j = 0; j < 8; ++j) t8[j] = f2bf(acc[i][j] + bxa[j]);
    unsigned short* p = xg + row * NG5 + bn * 128 + 8 * tx;
    *(ushort4*)(p)     = make_ushort4(t8[0], t8[1], t8[2], t8[3]);
    *(ushort4*)(p + 4) = make_ushort4(t8[4], t8[5], t8[6], t8[7]);
  }
}

// ---------------------------------------------------------------- recurrence
// Block b owns elements [8b,8b+8). Wave w: gate rg=w&3, half hf=w>>2.
// Operand columns per lane: {1024*hf + 256*k + 4*lane + m} read from LDS.
__global__ __launch_bounds__(NTHR, 2) void fplstm_recur(
    const unsigned short* __restrict__ xg,
    float* hrep, float* arep,
    const float* __restrict__ Wh, const float* __restrict__ bh,
    const float* __restrict__ Wm, const float* __restrict__ bm,
    float* __restrict__ out)
{
  const int tid  = threadIdx.x;
  const int b    = blockIdx.x;
  const int w    = tid >> 6;
  const int lane = tid & 63;
  const int rg   = w & 3;
  const int hf   = w >> 2;
  const int colbase = 1024 * hf + 4 * lane;

  // ---- one-time: weights -> registers ----
  float whr[8][16];
#pragma unroll
  for (int r = 0; r < 8; ++r) {
    const float* wp = Wh + (size_t)(rg * MEM + 8 * b + r) * MEM + colbase;
#pragma unroll
    for (int k = 0; k < 4; ++k) {
      float4 v = *(const float4*)(wp + 256 * k);
      whr[r][4*k+0] = v.x; whr[r][4*k+1] = v.y; whr[r][4*k+2] = v.z; whr[r][4*k+3] = v.w;
    }
  }
  float wmr[2][16];
#pragma unroll
  for (int r = 0; r < 2; ++r) {
    const float* wp = Wm + (size_t)(8 * b + 2 * rg + r) * MEM + colbase;
#pragma unroll
    for (int k = 0; k < 4; ++k) {
      float4 v = *(const float4*)(wp + 256 * k);
      wmr[r][4*k+0] = v.x; wmr[r][4*k+1] = v.y; wmr[r][4*k+2] = v.z; wmr[r][4*k+3] = v.w;
    }
  }

  float bhv0 = 0, bhv1 = 0, bhv2 = 0, bhv3 = 0, bmv = 0;
  if (tid < 8) {
    bhv0 = bh[0 * MEM + 8 * b + tid];
    bhv1 = bh[1 * MEM + 8 * b + tid];
    bhv2 = bh[2 * MEM + 8 * b + tid];
    bhv3 = bh[3 * MEM + 8 * b + tid];
    bmv  = bm[8 * b + tid];
  }

  __shared__ float hs[MEM];         // staged h (phase A) / a (phase B)
  __shared__ float redL[8][8];
  __shared__ float ghL[32];
  __shared__ float redM[8][2];

  // collector addressing: wave w handles lines [32w, 32w+32) of copy b&7;
  // lane covers line0 = 32w + (lane>>2) and line1 = line0+16, quarter q.
  const int copy  = b & 7;
  const int q     = lane & 3;
  const int line0 = 32 * w + (lane >> 2);
  const int line1 = line0 + 16;
  const float* hl0 = hrep + (size_t)(copy * NBLK + line0) * 16 + q * 4;
  const float* hl1 = hrep + (size_t)(copy * NBLK + line1) * 16 + q * 4;
  const float* al0 = arep + (size_t)(copy * NBLK + line0) * 16 + q * 4;
  const float* al1 = arep + (size_t)(copy * NBLK + line1) * 16 + q * 4;

  // publisher addressing (wave 0): data lane -> copy lane>>3, elem lane&7;
  // tag lanes 0..7 -> copy lane.
  float* a_dst = arep + (size_t)((lane >> 3) * NBLK + b) * 16 + (lane & 7);
  float* h_dst = hrep + (size_t)((lane >> 3) * NBLK + b) * 16 + (lane & 7);
  int* a_tag = (int*)(arep + (size_t)(lane * NBLK + b) * 16 + 8);
  int* h_tag = (int*)(hrep + (size_t)(lane * NBLK + b) * 16 + 8);

  float c_e = 0.0f, h_last = 0.0f;

  for (int t = 0; t < T_STEPS; ++t) {
    // prefetch xg row t (plain cached loads; drained by first poll's vmcnt)
    float xv0 = 0, xv1 = 0, xv2 = 0, xv3 = 0, xv4 = 0;
    if (tid < 8) {
      const unsigned short* xp = xg + (size_t)t * NG5 + 8 * b + tid;
      xv0 = bf2f(xp[0]);
      xv1 = bf2f(xp[1 * MEM]);
      xv2 = bf2f(xp[2 * MEM]);
      xv3 = bf2f(xp[3 * MEM]);
      xv4 = bf2f(xp[4 * MEM]);
    }

    // ---- phase A: poll+collect h lines (tag >= 2t), stage to LDS ----
    {
      const int tgt = 2 * t;
      int4 v0, v1;
      for (;;) {
        asm volatile("global_load_dwordx4 %0, %2, off sc0 sc1\n\t"
                     "global_load_dwordx4 %1, %3, off sc0 sc1\n\t"
                     "s_waitcnt vmcnt(0)"
                     : "=v"(v0), "=v"(v1) : "v"(hl0), "v"(hl1) : "memory");
        bool ok = (q != 2) || (v0.x >= tgt && v1.x >= tgt);
        if (__all(ok)) break;
      }
      if (q < 2) {
        *(int4*)&hs[8 * line0 + 4 * q] = v0;
        *(int4*)&hs[8 * line1 + 4 * q] = v1;
      }
    }
    __syncthreads();

    // ---- Wh@h partials ----
    float hreg[16];
#pragma unroll
    for (int k = 0; k < 4; ++k) {
      float4 v = *(const float4*)&hs[colbase + 256 * k];
      hreg[4*k+0] = v.x; hreg[4*k+1] = v.y; hreg[4*k+2] = v.z; hreg[4*k+3] = v.w;
    }
    float acc[8];
#pragma unroll
    for (int r = 0; r < 8; ++r) {
      float s = 0.0f;
#pragma unroll
      for (int j = 0; j < 16; ++j) s = fmaf(whr[r][j], hreg[j], s);
      acc[r] = s;
    }
    // butterfly reduce-scatter
    float v4[4];
    {
      const int b0 = lane & 1;
#pragma unroll
      for (int i = 0; i < 4; ++i) {
        float sent = b0 ? acc[i] : acc[4 + i];
        float got  = __shfl_xor(sent, 1, 64);
        v4[i] = (b0 ? acc[4 + i] : acc[i]) + got;
      }
    }
    float v2[2];
    {
      const int b1 = (lane >> 1) & 1;
#pragma unroll
      for (int i = 0; i < 2; ++i) {
        float sent = b1 ? v4[i] : v4[2 + i];
        float got  = __shfl_xor(sent, 2, 64);
        v2[i] = (b1 ? v4[2 + i] : v4[i]) + got;
      }
    }
    float v1r;
    {
      const int b2 = (lane >> 2) & 1;
      float sent = b2 ? v2[0] : v2[1];
      float got  = __shfl_xor(sent, 4, 64);
      v1r = (b2 ? v2[1] : v2[0]) + got;
    }
    v1r += __shfl_xor(v1r, 8, 64);
    v1r += __shfl_xor(v1r, 16, 64);
    v1r += __shfl_xor(v1r, 32, 64);
    if (lane < 8) {
      const int r = 4 * (lane & 1) + 2 * ((lane >> 1) & 1) + ((lane >> 2) & 1);
      redL[w][r] = v1r;
    }
    __syncthreads();

    // ---- wave 0: gates, publish a (8 copies) + tags ----
    float g_i = 0, g_o = 0, g_fc = 0, a_e = 0;
    if (w == 0) {
      if (tid < 32)
        ghL[tid] = redL[tid >> 3][tid & 7] + redL[(tid >> 3) + 4][tid & 7];
      if (tid < 8) {
        float gi = sigmoidf_(xv0 + ghL[tid]      + bhv0);
        float go = sigmoidf_(xv1 + ghL[8 + tid]  + bhv1);
        float gz = sigmoidf_(xv2 + ghL[16 + tid] + bhv2);
        float gf = sigmoidf_(xv3 + ghL[24 + tid] + bhv3);
        a_e = gz * tanhf_(c_e);
        g_i = gi; g_o = go; g_fc = gf * c_e;
      }
      float av = __shfl(a_e, lane & 7, 64);
      store_f_cc(a_dst, av);
      drain_stores();
      if (lane < 8) store_i_cc(a_tag, 2 * t + 1);
    }

    // ---- phase B: poll+collect a lines (tag >= 2t+1), stage to LDS ----
    // (hs reuse safe: all hreg ds_reads precede the redL barrier)
    {
      const int tgt = 2 * t + 1;
      int4 v0, v1;
      for (;;) {
        asm volatile("global_load_dwordx4 %0, %2, off sc0 sc1\n\t"
                     "global_load_dwordx4 %1, %3, off sc0 sc1\n\t"
                     "s_waitcnt vmcnt(0)"
                     : "=v"(v0), "=v"(v1) : "v"(al0), "v"(al1) : "memory");
        bool ok = (q != 2) || (v0.x >= tgt && v1.x >= tgt);
        if (__all(ok)) break;
      }
      if (q < 2) {
        *(int4*)&hs[8 * line0 + 4 * q] = v0;
        *(int4*)&hs[8 * line1 + 4 * q] = v1;
      }
    }
    __syncthreads();

    // ---- Wm@a partials ----
    float areg[16];
#pragma unroll
    for (int k = 0; k < 4; ++k) {
      float4 v = *(const float4*)&hs[colbase + 256 * k];
      areg[4*k+0] = v.x; areg[4*k+1] = v.y; areg[4*k+2] = v.z; areg[4*k+3] = v.w;
    }
    float am0 = 0.0f, am1 = 0.0f;
#pragma unroll
    for (int j = 0; j < 16; ++j) am0 = fmaf(wmr[0][j], areg[j], am0);
#pragma unroll
    for (int j = 0; j < 16; ++j) am1 = fmaf(wmr[1][j], areg[j], am1);
    {
      float sent = (lane & 1) ? am0 : am1;
      float got  = __shfl_xor(sent, 1, 64);
      float vv = ((lane & 1) ? am1 : am0) + got;
      vv += __shfl_xor(vv, 2, 64);
      vv += __shfl_xor(vv, 4, 64);
      vv += __shfl_xor(vv, 8, 64);
      vv += __shfl_xor(vv, 16, 64);
      vv += __shfl_xor(vv, 32, 64);
      if (lane < 2) redM[w][lane] = vv;
    }
    __syncthreads();

    // ---- wave 0: c/h update, publish h (8 copies) + tags ----
    if (w == 0) {
      if (tid < 8) {
        float mg = redM[tid >> 1][tid & 1] + redM[(tid >> 1) + 4][tid & 1];
        float u  = tanhf_(xv4 + mg + bmv);
        c_e    = fmaf(g_i, u, g_fc);
        h_last = g_o * tanhf_(c_e);
      }
      float hv = __shfl(h_last, lane & 7, 64);
      store_f_cc(h_dst, hv);
      drain_stores();
      if (lane < 8) store_i_cc(h_tag, 2 * t + 2);
    }
    // next iteration's phase-A poll (tag >= 2t+2) is the barrier
  }

  if (tid < 8) out[8 * b + tid] = h_last;
}

// ---------------------------------------------------------------- launch
extern "C" void kernel_launch(void* const* d_in, const int* in_sizes, int n_in,
                              void* d_out, int out_size, void* d_ws, size_t ws_size,
                              hipStream_t stream) {
  const float* inputs = (const float*)d_in[0];
  const float* Wx     = (const float*)d_in[1];
  const float* bx     = (const float*)d_in[2];
  const float* Wh     = (const float*)d_in[3];
  const float* bh     = (const float*)d_in[4];
  const float* Wm     = (const float*)d_in[5];
  const float* bm     = (const float*)d_in[6];
  float* out = (float*)d_out;
  char* ws = (char*)d_ws;

  if (ws_size < WS_NEEDED) {
    fprintf(stderr, "FPLSTM: ws_size %zu < needed %zu -- cannot run\n",
            ws_size, (size_t)WS_NEEDED);
    return;
  }

  unsigned short* xg = (unsigned short*)ws;
  float* hrep = (float*)(ws + HREP_OFF);
  float* arep = (float*)(ws + AREP_OFF);

  fplstm_init<<<1, 256, 0, stream>>>((int*)hrep);
  fplstm_gemm<<<dim3(80, 64), 256, 0, stream>>>(inputs, Wx, bx, xg);

  void* args[] = {(void*)&xg, (void*)&hrep, (void*)&arep,
                  (void*)&Wh, (void*)&bh, (void*)&Wm, (void*)&bm, (void*)&out};
  hipError_t e = hipLaunchCooperativeKernel((void*)fplstm_recur, dim3(NBLK),
                                            dim3(NTHR), args, 0, stream);
  if (e != hipSuccess) {
    fprintf(stderr, "FPLSTM: coop launch failed (%d), plain launch\n", (int)e);
    fplstm_recur<<<dim3(NBLK), dim3(NTHR), 0, stream>>>(
        xg, hrep, arep, Wh, bh, Wm, bm, out);
  }
}